// Round 12
// baseline (972.275 us; speedup 1.0000x reference)
//
#include <hip/hip_runtime.h>
#include <hip/hip_fp16.h>

#define BP_EPS 1e-12f
#define BP_K 8
#define LOG_C 2.0f          // centering offset: stored = log(m) + LOG_C
#define CLAMP_SAFE -27.70f  // ln(1e-12) = -27.631; 0.07 margin -> near-threshold goes slow path

typedef __attribute__((ext_vector_type(8))) _Float16 half8;

// ===========================================================================
// Build (direct-atomic, 3 passes):
//  k_deg:   deg[node] via global atomics (L2-resident counters).
//  scan:    row = exclusive scan of deg (3 tiny kernels); cur = row copy.
//  k_place: per undirected edge e: pu=cur[u]++, pv=cur[v]++;
//           eid[pu]=e+Eu (msgs row of v->u), eid[pv]=e;
//           rev[pu]=pv, rev[pv]=pu  (both slots known here -> no extra pass).
// Slot order within a row is nondeterministic (atomic order) -- reduce is a
// product, order only perturbs fp rounding ~1e-7, far below fp16 storage.
// Messages LIVE in slot order: iteration reads sequential, writes to rev[j].
// ===========================================================================

__global__ void k_zero(int* __restrict__ deg, int n1) {
    int i = blockIdx.x * blockDim.x + threadIdx.x;
    if (i < n1) deg[i] = 0;
}

__global__ void k_deg(const int* __restrict__ src, const int* __restrict__ dst,
                      int* __restrict__ deg, int Eu) {
    int e = blockIdx.x * blockDim.x + threadIdx.x;
    if (e < Eu) {
        atomicAdd(&deg[src[e]], 1);
        atomicAdd(&deg[dst[e]], 1);
    }
}

__global__ void k_scan1(const int* __restrict__ deg, int* __restrict__ row,
                        int* __restrict__ bsum, int n1) {
    __shared__ int buf[1024];
    int i = blockIdx.x * 1024 + threadIdx.x;
    int v = (i < n1) ? deg[i] : 0;
    buf[threadIdx.x] = v;
    __syncthreads();
    for (int off = 1; off < 1024; off <<= 1) {
        int x = (threadIdx.x >= off) ? buf[threadIdx.x - off] : 0;
        __syncthreads();
        buf[threadIdx.x] += x;
        __syncthreads();
    }
    if (i < n1) row[i] = buf[threadIdx.x] - v;
    if (threadIdx.x == 1023) bsum[blockIdx.x] = buf[1023];
}

__global__ void k_scan2(int* __restrict__ bsum, int nb) {
    __shared__ int buf[1024];
    int t = threadIdx.x;
    int v = (t < nb) ? bsum[t] : 0;
    buf[t] = v;
    __syncthreads();
    for (int off = 1; off < 1024; off <<= 1) {
        int x = (t >= off) ? buf[t - off] : 0;
        __syncthreads();
        buf[t] += x;
        __syncthreads();
    }
    if (t < nb) bsum[t] = buf[t] - v;   // exclusive across blocks
}

__global__ void k_scan3(int* __restrict__ row, const int* __restrict__ bsum,
                        int* __restrict__ cur, int n1, int n) {
    int i = blockIdx.x * blockDim.x + threadIdx.x;
    if (i < n1) {
        int r = row[i] + bsum[i >> 10];
        row[i] = r;
        if (i < n) cur[i] = r;
    }
}

__global__ void k_place(const int* __restrict__ src, const int* __restrict__ dst,
                        int* __restrict__ cur, int* __restrict__ eid,
                        int* __restrict__ rev, int Eu) {
    int e = blockIdx.x * blockDim.x + threadIdx.x;
    if (e >= Eu) return;
    int u = src[e], v = dst[e];
    int pu = atomicAdd(&cur[u], 1);
    int pv = atomicAdd(&cur[v], 1);
    eid[pu] = e + Eu;   // slot at u holds (v->u) = msgs row e+Eu
    eid[pv] = e;        // slot at v holds (u->v) = msgs row e
    rev[pu] = pv;
    rev[pv] = pu;
}

// LP[i][k] = log(max(prior, eps)).
__global__ void k_lp(const float* __restrict__ prior, float* __restrict__ LP, int n8) {
    int i = blockIdx.x * blockDim.x + threadIdx.x;
    if (i < n8) LP[i] = __logf(fmaxf(prior[i], BP_EPS));
}

// ---- emit from clamped b-vector (bit-identical to previous slow path) ----
__device__ inline half8 bp_emit_bb(const float* bb, const float* psi) {
    float mn[BP_K];
    float sum = 0.0f;
#pragma unroll
    for (int jj = 0; jj < BP_K; ++jj) {
        float acc = 0.0f;
#pragma unroll
        for (int k = 0; k < BP_K; ++k) acc += bb[k] * psi[k * BP_K + jj];
        mn[jj] = acc;
        sum += acc;
    }
    float inv = 1.0f / fmaxf(sum, BP_EPS);
    half8 o;
#pragma unroll
    for (int jj = 0; jj < BP_K; ++jj)
        o[jj] = (_Float16)(__logf(fmaxf(mn[jj] * inv, BP_EPS)) + LOG_C);
    return o;
}

__device__ inline half8 bp_emit(const float* s, const float* lm, const float* psi) {
    float bb[BP_K];
#pragma unroll
    for (int k = 0; k < BP_K; ++k)
        bb[k] = fmaxf(__expf(s[k] - lm[k]), BP_EPS);
    return bp_emit_bb(bb, psi);
}

// all 8 classes safely below the EPS clamp? (then output == wbar exactly)
__device__ inline bool bp_allclamp(const float* s, const float* lm) {
    float m = s[0] - lm[0];
#pragma unroll
    for (int k = 1; k < BP_K; ++k) m = fmaxf(m, s[k] - lm[k]);
    return m < CLAMP_SAFE;
}

// ===========================================================================
// Fused iteration (half-wave per node): sequential W read (iter-1: fp32
// gather via eid), trips 0/1 register-cached, shuffle-reduce S (+log prior),
// then per cached slot: if all-clamped emit precomputed wbar, else full
// (bit-identical) emit. Scatter-write 16B to Wn[rev[j]] (permutation).
// ===========================================================================

template <bool FIRST>
__global__ void __launch_bounds__(256) k_step(
        const float* __restrict__ msgs, const _Float16* __restrict__ Wc,
        const int* __restrict__ eid, const int* __restrict__ row,
        const int* __restrict__ rev, const float* __restrict__ LP,
        const float* __restrict__ potential, _Float16* __restrict__ Wn,
        int n) {
    __shared__ float psi[BP_K * BP_K];
    if (threadIdx.x < BP_K * BP_K) psi[threadIdx.x] = expf(potential[threadIdx.x]);
    __syncthreads();

    // constant message produced whenever all classes clamp at EPS
    float bbc[BP_K];
#pragma unroll
    for (int k = 0; k < BP_K; ++k) bbc[k] = BP_EPS;
    half8 wbar = bp_emit_bb(bbc, psi);

    int half = threadIdx.x >> 5;
    int sl = threadIdx.x & 31;
    int i = blockIdx.x * 8 + half;
    if (i >= n) return;

    int r0 = row[i];
    int r1 = row[i + 1];
    int j0 = r0 + sl;
    int j1 = j0 + 32;
    bool h0 = j0 < r1;
    bool h1 = j1 < r1;

    float s[BP_K];
#pragma unroll
    for (int k = 0; k < BP_K; ++k) s[k] = 0.0f;

    float lm0[BP_K], lm1[BP_K];
    int rv0 = 0, rv1 = 0;

#define LOADLM(J, LM)                                                         \
    {                                                                         \
        if (FIRST) {                                                          \
            int id = eid[J];                                                  \
            const float4* m4 = (const float4*)(msgs + (size_t)id * BP_K);     \
            float4 x = m4[0], y = m4[1];                                      \
            float v[BP_K] = {x.x, x.y, x.z, x.w, y.x, y.y, y.z, y.w};         \
            _Pragma("unroll")                                                 \
            for (int k = 0; k < BP_K; ++k)                                    \
                LM[k] = __logf(fmaxf(v[k], BP_EPS));                          \
        } else {                                                              \
            half8 h = *(const half8*)(Wc + (size_t)(J) * BP_K);               \
            _Pragma("unroll")                                                 \
            for (int k = 0; k < BP_K; ++k) LM[k] = (float)h[k] - LOG_C;       \
        }                                                                     \
    }

    if (h0) {
        rv0 = rev[j0];
        LOADLM(j0, lm0);
#pragma unroll
        for (int k = 0; k < BP_K; ++k) s[k] += lm0[k];
    }
    if (h1) {
        rv1 = rev[j1];
        LOADLM(j1, lm1);
#pragma unroll
        for (int k = 0; k < BP_K; ++k) s[k] += lm1[k];
    }
    for (int j = j0 + 64; j < r1; j += 32) {
        float t[BP_K];
        LOADLM(j, t);
#pragma unroll
        for (int k = 0; k < BP_K; ++k) s[k] += t[k];
    }

#pragma unroll
    for (int off = 16; off >= 1; off >>= 1) {
#pragma unroll
        for (int k = 0; k < BP_K; ++k) s[k] += __shfl_xor(s[k], off);
    }

    {   // fold in log prior (all lanes need it for the emit phase)
        const float4* lp4 = (const float4*)(LP + (size_t)i * BP_K);
        float4 la = lp4[0], lb = lp4[1];
        s[0] += la.x; s[1] += la.y; s[2] += la.z; s[3] += la.w;
        s[4] += lb.x; s[5] += lb.y; s[6] += lb.z; s[7] += lb.w;
    }

    if (h0)
        *(half8*)(Wn + (size_t)rv0 * BP_K) =
            bp_allclamp(s, lm0) ? wbar : bp_emit(s, lm0, psi);
    if (h1)
        *(half8*)(Wn + (size_t)rv1 * BP_K) =
            bp_allclamp(s, lm1) ? wbar : bp_emit(s, lm1, psi);
    for (int j = j0 + 64; j < r1; j += 32) {
        float t[BP_K];
        LOADLM(j, t);
        int rv = rev[j];
        *(half8*)(Wn + (size_t)rv * BP_K) =
            bp_allclamp(s, t) ? wbar : bp_emit(s, t, psi);
    }
#undef LOADLM
}

// Final beliefs: sequential row read, normalize with prior (via LP).
__global__ void __launch_bounds__(256) k_belief(
        const _Float16* __restrict__ Wc, const int* __restrict__ row,
        const float* __restrict__ LP, float* __restrict__ out, int n) {
    int half = threadIdx.x >> 5;
    int sl = threadIdx.x & 31;
    int i = blockIdx.x * 8 + half;
    if (i >= n) return;

    int r0 = row[i];
    int r1 = row[i + 1];

    float s[BP_K];
#pragma unroll
    for (int k = 0; k < BP_K; ++k) s[k] = 0.0f;

    for (int j = r0 + sl; j < r1; j += 32) {
        half8 h = *(const half8*)(Wc + (size_t)j * BP_K);
#pragma unroll
        for (int k = 0; k < BP_K; ++k) s[k] += (float)h[k] - LOG_C;
    }

#pragma unroll
    for (int off = 16; off >= 1; off >>= 1) {
#pragma unroll
        for (int k = 0; k < BP_K; ++k) s[k] += __shfl_xor(s[k], off);
    }

    if (sl == 0) {
        const float4* lp4 = (const float4*)(LP + (size_t)i * BP_K);
        float4 la = lp4[0], lb = lp4[1];
        float lp[BP_K] = {la.x, la.y, la.z, la.w, lb.x, lb.y, lb.z, lb.w};
        float b[BP_K];
        float sum = 0.0f;
#pragma unroll
        for (int k = 0; k < BP_K; ++k) {
            b[k] = fmaxf(__expf(s[k] + lp[k]), BP_EPS);
            sum += b[k];
        }
        float inv = 1.0f / fmaxf(sum, BP_EPS);
        float4* o4 = (float4*)(out + (size_t)i * BP_K);
        o4[0] = {b[0] * inv, b[1] * inv, b[2] * inv, b[3] * inv};
        o4[1] = {b[4] * inv, b[5] * inv, b[6] * inv, b[7] * inv};
    }
}

extern "C" void kernel_launch(void* const* d_in, const int* in_sizes, int n_in,
                              void* d_out, int out_size, void* d_ws, size_t ws_size,
                              hipStream_t stream) {
    const float* prior     = (const float*)d_in[0];
    const float* msgs      = (const float*)d_in[1];
    const float* potential = (const float*)d_in[2];
    const int*   src       = (const int*)d_in[3];
    const int*   dst       = (const int*)d_in[4];
    const int ITERS = 5;   // fixed by setup_inputs

    int n  = in_sizes[0] / BP_K;
    int E  = in_sizes[3];
    int Eu = E / 2;
    int n1 = n + 1;
    int nsb = (n1 + 1023) / 1024;

    char* w = (char*)d_ws;
    _Float16* W1 = (_Float16*)w;  w += (size_t)E * BP_K * sizeof(_Float16);
    _Float16* W2 = (_Float16*)w;  w += (size_t)E * BP_K * sizeof(_Float16);
    float* LP    = (float*)w;     w += (size_t)n * BP_K * sizeof(float);
    int*   row   = (int*)w;       w += (size_t)n1 * sizeof(int);
    int*   deg   = (int*)w;       w += (size_t)n1 * sizeof(int);
    int*   cur   = (int*)w;       w += (size_t)n * sizeof(int);
    int*   bsum  = (int*)w;       w += (size_t)1024 * sizeof(int);
    int*   rev   = (int*)w;       w += (size_t)E * sizeof(int);
    int*   eid   = (int*)w;       w += (size_t)E * sizeof(int);

    float* out = (float*)d_out;

    dim3 blk(256);
    dim3 grdEu((Eu + 255) / 256);
    dim3 grdN1((n1 + 255) / 256);
    dim3 grdNode((n + 7) / 8);     // 8 half-waves/block, half-wave per node

    // --- build: direct-atomic CSR (row/eid/rev), 6 small kernels ---
    k_zero <<<grdN1, blk, 0, stream>>>(deg, n1);
    k_deg  <<<grdEu, blk, 0, stream>>>(src, dst, deg, Eu);
    k_scan1<<<nsb, 1024, 0, stream>>>(deg, row, bsum, n1);
    k_scan2<<<1, 1024, 0, stream>>>(bsum, nsb);
    k_scan3<<<grdN1, blk, 0, stream>>>(row, bsum, cur, n1, n);
    k_place<<<grdEu, blk, 0, stream>>>(src, dst, cur, eid, rev, Eu);
    k_lp   <<<(n * BP_K + 255) / 256, blk, 0, stream>>>(prior, LP, n * BP_K);

    // --- iteration 1: fp32 gather (register-cached, single pass) ---
    k_step<true><<<grdNode, blk, 0, stream>>>(msgs, nullptr, eid, row, rev,
                                              LP, potential, W1, n);

    // --- iterations 2..5: sequential read + clamp fast-path + scatter write ---
    _Float16* curW = W1;
    _Float16* nxtW = W2;
    for (int it = 1; it < ITERS; ++it) {
        k_step<false><<<grdNode, blk, 0, stream>>>(nullptr, curW, nullptr, row,
                                                   rev, LP, potential, nxtW, n);
        _Float16* tmp = curW; curW = nxtW; nxtW = tmp;
    }

    // --- final beliefs ---
    k_belief<<<grdNode, blk, 0, stream>>>(curW, row, LP, out, n);
}

// Round 13
// 521.271 us; speedup vs baseline: 1.8652x; 1.8652x over previous
//
#include <hip/hip_runtime.h>
#include <hip/hip_fp16.h>

#define BP_EPS 1e-12f
#define BP_K 8
#define LOG_C 2.0f          // centering offset: stored = log(m) + LOG_C
#define CLAMP_SAFE -27.70f  // exact-test threshold (ln 1e-12 = -27.631, margin .07)
#define THR_HOT    -27.80f  // conservative node-level pre-test (extra fp-sum margin)
#define BSH 6               // nodes per bucket = 64
#define BNODES 64
#define NB1 512             // edge chunks for hist + scatter

typedef __attribute__((ext_vector_type(8))) _Float16 half8;

// ===========================================================================
// W lives in CSR slot order, represented as: wbar everywhere + exceptions.
// iter1 = only full pass (reads fp32 input msgs); writes only non-clamped
// emits into Wex and records them in XS. iters 2..5 touch only nodes that are
// hot (deg small) or adjacent (either side) to an XS slot: mark -> sparse
// recompute (bit-identical reduce/emit, changes staged) -> apply.
// ===========================================================================

// ---- bucket-strip build (dense scatter runs; proven R0-R9) ----------------
__global__ void k_hist(const int* __restrict__ src, const int* __restrict__ dst,
                       int* __restrict__ G, int Eu, int nbuck) {
    extern __shared__ int h[];
    for (int i = threadIdx.x; i < nbuck; i += blockDim.x) h[i] = 0;
    __syncthreads();
    int per = (Eu + NB1 - 1) / NB1;
    int s0 = blockIdx.x * per;
    int s1 = min(s0 + per, Eu);
    for (int e = s0 + threadIdx.x; e < s1; e += blockDim.x) {
        atomicAdd(&h[src[e] >> BSH], 1);
        atomicAdd(&h[dst[e] >> BSH], 1);
    }
    __syncthreads();
    for (int b = threadIdx.x; b < nbuck; b += blockDim.x)
        G[blockIdx.x * nbuck + b] = h[b];
}

__global__ void k_scanG(const int* __restrict__ G, int* __restrict__ Gpre,
                        int* __restrict__ total, int nbuck) {
    __shared__ int buf[NB1];
    int b = blockIdx.x;
    int t = threadIdx.x;
    int v = G[t * nbuck + b];
    buf[t] = v;
    __syncthreads();
    for (int off = 1; off < NB1; off <<= 1) {
        int x = (t >= off) ? buf[t - off] : 0;
        __syncthreads();
        buf[t] += x;
        __syncthreads();
    }
    Gpre[b * NB1 + t] = buf[t] - v;
    if (t == NB1 - 1) total[b] = buf[t];
}

__global__ void k_scanT(const int* __restrict__ total, int* __restrict__ base,
                        int nbuck, int* __restrict__ row_n, int E) {
    __shared__ int buf[1024];
    int t = threadIdx.x;
    int carry = 0;
    for (int s = 0; s < nbuck; s += 1024) {
        int i = s + t;
        int v = (i < nbuck) ? total[i] : 0;
        buf[t] = v;
        __syncthreads();
        for (int off = 1; off < 1024; off <<= 1) {
            int x = (t >= off) ? buf[t - off] : 0;
            __syncthreads();
            buf[t] += x;
            __syncthreads();
        }
        if (i < nbuck) base[i] = carry + buf[t] - v;
        carry += buf[1023];
        __syncthreads();
    }
    if (t == 0) { base[nbuck] = carry; *row_n = E; }
}

__global__ void k_scatter(const int* __restrict__ src, const int* __restrict__ dst,
                          const int* __restrict__ Gpre, const int* __restrict__ base,
                          int2* __restrict__ items, int Eu, int nbuck) {
    extern __shared__ int cur[];
    int blk = blockIdx.x;
    for (int i = threadIdx.x; i < nbuck; i += blockDim.x)
        cur[i] = base[i] + Gpre[i * NB1 + blk];
    __syncthreads();
    int per = (Eu + NB1 - 1) / NB1;
    int s0 = blk * per;
    int s1 = min(s0 + per, Eu);
    for (int e = s0 + threadIdx.x; e < s1; e += blockDim.x) {
        int u = src[e], v = dst[e];
        int pu = atomicAdd(&cur[u >> BSH], 1);
        items[pu] = make_int2(u, (e << 1) | 1);
        int pv = atomicAdd(&cur[v >> BSH], 1);
        items[pv] = make_int2(v, (e << 1) | 0);
    }
}

// bucket -> per-node CSR; emit pos[payload]=slot, eid[slot]=msgs row, nod[slot].
__global__ void k_csr(const int2* __restrict__ items, const int* __restrict__ base,
                      int* __restrict__ row, int* __restrict__ pos,
                      int* __restrict__ eid, int* __restrict__ nod, int n, int Eu) {
    __shared__ int deg[BNODES];
    __shared__ int cur[BNODES];
    int b = blockIdx.x;
    int lo = base[b], hi = base[b + 1];
    int node0 = b << BSH;
    if (threadIdx.x < BNODES) deg[threadIdx.x] = 0;
    __syncthreads();
    for (int i = lo + threadIdx.x; i < hi; i += blockDim.x)
        atomicAdd(&deg[items[i].x - node0], 1);
    __syncthreads();
    if (threadIdx.x == 0) {
        int acc = 0;
        for (int t = 0; t < BNODES; ++t) { int d = deg[t]; deg[t] = acc; acc += d; }
    }
    __syncthreads();
    if (threadIdx.x < BNODES) {
        int node = node0 + threadIdx.x;
        if (node < n) row[node] = lo + deg[threadIdx.x];
        cur[threadIdx.x] = deg[threadIdx.x];
    }
    __syncthreads();
    for (int i = lo + threadIdx.x; i < hi; i += blockDim.x) {
        int2 x = items[i];
        int p = atomicAdd(&cur[x.x - node0], 1);
        int slot = lo + p;
        pos[x.y] = slot;
        eid[slot] = (x.y >> 1) + (x.y & 1) * Eu;
        nod[slot] = x.x;
    }
}

// rev from pos pairs: slots pos[2e] and pos[2e+1] are mutual reverses.
__global__ void k_rev(const int* __restrict__ pos, int* __restrict__ rev, int Eu) {
    int e = blockIdx.x * blockDim.x + threadIdx.x;
    if (e < Eu) {
        int2 p = ((const int2*)pos)[e];
        rev[p.x] = p.y;
        rev[p.y] = p.x;
    }
}

__global__ void k_lp(const float* __restrict__ prior, float* __restrict__ LP, int n8) {
    int i = blockIdx.x * blockDim.x + threadIdx.x;
    if (i < n8) LP[i] = __logf(fmaxf(prior[i], BP_EPS));
}

// zero per-launch state: node flags, slot bitmap, counters.
__global__ void k_zero(int* __restrict__ nflag, unsigned int* __restrict__ bmap,
                       int* __restrict__ cnts, int n, int nb) {
    int i = blockIdx.x * blockDim.x + threadIdx.x;
    int st = gridDim.x * blockDim.x;
    for (int j = i; j < n; j += st) nflag[j] = 0;
    for (int j = i; j < nb; j += st) bmap[j] = 0;
    if (i < 16) cnts[i] = 0;
}

// ---- emit math (identical to R12's hardware-verified path) ----------------
__device__ inline half8 bp_emit_bb(const float* bb, const float* psi) {
    float mn[BP_K];
    float sum = 0.0f;
#pragma unroll
    for (int jj = 0; jj < BP_K; ++jj) {
        float acc = 0.0f;
#pragma unroll
        for (int k = 0; k < BP_K; ++k) acc += bb[k] * psi[k * BP_K + jj];
        mn[jj] = acc;
        sum += acc;
    }
    float inv = 1.0f / fmaxf(sum, BP_EPS);
    half8 o;
#pragma unroll
    for (int jj = 0; jj < BP_K; ++jj)
        o[jj] = (_Float16)(__logf(fmaxf(mn[jj] * inv, BP_EPS)) + LOG_C);
    return o;
}

__device__ inline half8 bp_emit(const float* s, const float* lm, const float* psi) {
    float bb[BP_K];
#pragma unroll
    for (int k = 0; k < BP_K; ++k)
        bb[k] = fmaxf(__expf(s[k] - lm[k]), BP_EPS);
    return bp_emit_bb(bb, psi);
}

__device__ inline bool bp_allclamp(const float* s, const float* lm) {
    float m = s[0] - lm[0];
#pragma unroll
    for (int k = 1; k < BP_K; ++k) m = fmaxf(m, s[k] - lm[k]);
    return m < CLAMP_SAFE;
}

__device__ inline bool neq16(const void* oldp, const half8& v) {
    uint4 x = *(const uint4*)oldp;
    uint4 y;
    __builtin_memcpy(&y, &v, 16);
    return ((x.x ^ y.x) | (x.y ^ y.y) | (x.z ^ y.z) | (x.w ^ y.w)) != 0u;
}

#define INIT_PSI()                                                             \
    __shared__ float psi[BP_K * BP_K];                                         \
    if (threadIdx.x < BP_K * BP_K) psi[threadIdx.x] = expf(potential[threadIdx.x]); \
    __syncthreads();

#define INIT_WBAR()                                                            \
    __shared__ __align__(16) unsigned short wsh[8];                            \
    if (threadIdx.x == 0) {                                                    \
        float bbc[BP_K];                                                       \
        for (int k = 0; k < BP_K; ++k) bbc[k] = BP_EPS;                        \
        half8 wb = bp_emit_bb(bbc, psi);                                       \
        for (int k = 0; k < BP_K; ++k) wsh[k] = ((unsigned short*)&wb)[k];     \
    }                                                                          \
    __syncthreads();                                                           \
    half8 wbar = *(half8*)wsh;

// fill Wex with wbar (sequential full-line stores, one time).
__global__ void __launch_bounds__(256) k_fill(
        _Float16* __restrict__ Wex, const float* __restrict__ potential, int E) {
    INIT_PSI();
    INIT_WBAR();
    int st = gridDim.x * blockDim.x;
    for (int s = blockIdx.x * blockDim.x + threadIdx.x; s < E; s += st)
        *(half8*)(Wex + (size_t)s * BP_K) = wbar;
}

// ===========================================================================
// iter1 (only full pass): half-wave per node, gather fp32 msgs via eid,
// trips 0/1 register-cached, butterfly S (+log prior); write ONLY non-clamped
// emits into Wex[rev[j]] and record them in XS (bitmap-dedup'd).
// ===========================================================================
__global__ void __launch_bounds__(256) k_step1(
        const float* __restrict__ msgs, const int* __restrict__ eid,
        const int* __restrict__ row, const int* __restrict__ rev,
        const float* __restrict__ LP, const float* __restrict__ potential,
        _Float16* __restrict__ Wex, int* __restrict__ XS,
        unsigned int* __restrict__ bmap, int* __restrict__ cnts, int n) {
    INIT_PSI();

    int half = threadIdx.x >> 5;
    int sl = threadIdx.x & 31;
    int i = blockIdx.x * 8 + half;
    if (i >= n) return;

    int r0 = row[i];
    int r1 = row[i + 1];
    int j0 = r0 + sl;
    int j1 = j0 + 32;
    bool h0 = j0 < r1;
    bool h1 = j1 < r1;

    float s[BP_K];
#pragma unroll
    for (int k = 0; k < BP_K; ++k) s[k] = 0.0f;

    float lm0[BP_K], lm1[BP_K];

#define LOADF(J, LM)                                                          \
    {                                                                         \
        int id = eid[J];                                                      \
        const float4* m4 = (const float4*)(msgs + (size_t)id * BP_K);         \
        float4 x = m4[0], y = m4[1];                                          \
        float v[BP_K] = {x.x, x.y, x.z, x.w, y.x, y.y, y.z, y.w};             \
        _Pragma("unroll")                                                     \
        for (int k = 0; k < BP_K; ++k) LM[k] = __logf(fmaxf(v[k], BP_EPS));   \
    }

    if (h0) {
        LOADF(j0, lm0);
#pragma unroll
        for (int k = 0; k < BP_K; ++k) s[k] += lm0[k];
    }
    if (h1) {
        LOADF(j1, lm1);
#pragma unroll
        for (int k = 0; k < BP_K; ++k) s[k] += lm1[k];
    }
    for (int j = j0 + 64; j < r1; j += 32) {
        float t[BP_K];
        LOADF(j, t);
#pragma unroll
        for (int k = 0; k < BP_K; ++k) s[k] += t[k];
    }

#pragma unroll
    for (int off = 16; off >= 1; off >>= 1) {
#pragma unroll
        for (int k = 0; k < BP_K; ++k) s[k] += __shfl_xor(s[k], off);
    }
    {
        const float4* lp4 = (const float4*)(LP + (size_t)i * BP_K);
        float4 la = lp4[0], lb = lp4[1];
        s[0] += la.x; s[1] += la.y; s[2] += la.z; s[3] += la.w;
        s[4] += lb.x; s[5] += lb.y; s[6] += lb.z; s[7] += lb.w;
    }

#define EMIT1(J, LM)                                                          \
    if (!bp_allclamp(s, LM)) {                                                \
        int rv = rev[J];                                                      \
        *(half8*)(Wex + (size_t)rv * BP_K) = bp_emit(s, LM, psi);             \
        unsigned int mbit = 1u << (rv & 31);                                  \
        if (!(atomicOr(&bmap[rv >> 5], mbit) & mbit)) {                       \
            int idx = atomicAdd(&cnts[0], 1);                                 \
            XS[idx] = rv;                                                     \
        }                                                                     \
    }

    if (h0) EMIT1(j0, lm0)
    if (h1) EMIT1(j1, lm1)
    for (int j = j0 + 64; j < r1; j += 32) {
        float t[BP_K];
        LOADF(j, t);
        EMIT1(j, t)
    }
#undef EMIT1
#undef LOADF
}

// ===========================================================================
// sparse iteration t: mark (hot nodes + XS neighborhoods) -> recompute marked
// nodes (bit-identical reduce/emit, stage changed values) -> apply.
// ===========================================================================
__global__ void __launch_bounds__(256) k_mark(
        const int* __restrict__ row, const float* __restrict__ LP,
        const float* __restrict__ potential, const int* __restrict__ XS,
        const int* __restrict__ nod, const int* __restrict__ rev,
        int* __restrict__ nflag, int* __restrict__ Alist,
        int* __restrict__ cnts, int aidx, int n) {
    INIT_PSI();
    INIT_WBAR();
    float lw[BP_K];
#pragma unroll
    for (int k = 0; k < BP_K; ++k) lw[k] = (float)wbar[k] - LOG_C;

    int tid = blockIdx.x * blockDim.x + threadIdx.x;
    int st = gridDim.x * blockDim.x;

#define MARK(NODE)                                                            \
    {                                                                         \
        int nd_ = (NODE);                                                     \
        if (atomicExch(&nflag[nd_], 1) == 0) {                                \
            int ix = atomicAdd(&cnts[aidx], 1);                               \
            Alist[ix] = nd_;                                                  \
        }                                                                     \
    }

    // hot nodes: all-wbar-input emit test could fail the clamp
    for (int i = tid; i < n; i += st) {
        float dg = (float)(row[i + 1] - row[i]);
        const float4* lp4 = (const float4*)(LP + (size_t)i * BP_K);
        float4 la = lp4[0], lb = lp4[1];
        float lp[BP_K] = {la.x, la.y, la.z, la.w, lb.x, lb.y, lb.z, lb.w};
        float m = -1e30f;
#pragma unroll
        for (int k = 0; k < BP_K; ++k)
            m = fmaxf(m, dg * lw[k] + lp[k] - lw[k]);
        if (m >= THR_HOT) MARK(i)
    }
    // XS neighborhoods: consumer (S changed) and producer (must re-emit)
    int xc = cnts[0];
    for (int e = tid; e < xc; e += st) {
        int s = XS[e];
        MARK(nod[s])
        MARK(nod[rev[s]])
    }
#undef MARK
}

__global__ void __launch_bounds__(256) k_sparse(
        const _Float16* __restrict__ Wex, const int* __restrict__ row,
        const int* __restrict__ rev, const float* __restrict__ LP,
        const float* __restrict__ potential, const int* __restrict__ Alist,
        int* __restrict__ nflag, _Float16* __restrict__ Wst,
        int* __restrict__ Sslot, int* __restrict__ cnts, int aidx, int sidx) {
    INIT_PSI();
    INIT_WBAR();

    int half = threadIdx.x >> 5;
    int sl = threadIdx.x & 31;
    int cntA = cnts[aidx];

    for (int a = blockIdx.x * 8 + half; a < cntA; a += gridDim.x * 8) {
        int i = Alist[a];
        int r0 = row[i];
        int r1 = row[i + 1];

        float s[BP_K];
#pragma unroll
        for (int k = 0; k < BP_K; ++k) s[k] = 0.0f;

        // bit-identical reduce: same per-lane j order, same butterfly
        for (int j = r0 + sl; j < r1; j += 32) {
            half8 h = *(const half8*)(Wex + (size_t)j * BP_K);
#pragma unroll
            for (int k = 0; k < BP_K; ++k) s[k] += (float)h[k] - LOG_C;
        }
#pragma unroll
        for (int off = 16; off >= 1; off >>= 1) {
#pragma unroll
            for (int k = 0; k < BP_K; ++k) s[k] += __shfl_xor(s[k], off);
        }
        {
            const float4* lp4 = (const float4*)(LP + (size_t)i * BP_K);
            float4 la = lp4[0], lb = lp4[1];
            s[0] += la.x; s[1] += la.y; s[2] += la.z; s[3] += la.w;
            s[4] += lb.x; s[5] += lb.y; s[6] += lb.z; s[7] += lb.w;
        }

        for (int j = r0 + sl; j < r1; j += 32) {
            half8 h = *(const half8*)(Wex + (size_t)j * BP_K);
            float lm[BP_K];
#pragma unroll
            for (int k = 0; k < BP_K; ++k) lm[k] = (float)h[k] - LOG_C;
            half8 nv = bp_allclamp(s, lm) ? wbar : bp_emit(s, lm, psi);
            int rv = rev[j];
            if (neq16(Wex + (size_t)rv * BP_K, nv)) {
                *(half8*)(Wst + (size_t)rv * BP_K) = nv;   // staged (no race)
                int idx = atomicAdd(&cnts[sidx], 1);
                Sslot[idx] = rv;
            }
        }
        if (sl == 0) nflag[i] = 0;   // reset for next iteration's mark
    }
}

__global__ void __launch_bounds__(256) k_apply(
        _Float16* __restrict__ Wex, const _Float16* __restrict__ Wst,
        const int* __restrict__ Sslot, int* __restrict__ XS,
        unsigned int* __restrict__ bmap, int* __restrict__ cnts, int sidx) {
    int cnt = cnts[sidx];
    int st = gridDim.x * blockDim.x;
    for (int e = blockIdx.x * blockDim.x + threadIdx.x; e < cnt; e += st) {
        int rv = Sslot[e];
        *(uint4*)(Wex + (size_t)rv * BP_K) = *(const uint4*)(Wst + (size_t)rv * BP_K);
        unsigned int mbit = 1u << (rv & 31);
        if (!(atomicOr(&bmap[rv >> 5], mbit) & mbit)) {
            int idx = atomicAdd(&cnts[0], 1);
            XS[idx] = rv;
        }
    }
}

// Final beliefs: sequential row read of Wex, normalize with prior (via LP).
__global__ void __launch_bounds__(256) k_belief(
        const _Float16* __restrict__ Wc, const int* __restrict__ row,
        const float* __restrict__ LP, float* __restrict__ out, int n) {
    int half = threadIdx.x >> 5;
    int sl = threadIdx.x & 31;
    int i = blockIdx.x * 8 + half;
    if (i >= n) return;

    int r0 = row[i];
    int r1 = row[i + 1];

    float s[BP_K];
#pragma unroll
    for (int k = 0; k < BP_K; ++k) s[k] = 0.0f;

    for (int j = r0 + sl; j < r1; j += 32) {
        half8 h = *(const half8*)(Wc + (size_t)j * BP_K);
#pragma unroll
        for (int k = 0; k < BP_K; ++k) s[k] += (float)h[k] - LOG_C;
    }

#pragma unroll
    for (int off = 16; off >= 1; off >>= 1) {
#pragma unroll
        for (int k = 0; k < BP_K; ++k) s[k] += __shfl_xor(s[k], off);
    }

    if (sl == 0) {
        const float4* lp4 = (const float4*)(LP + (size_t)i * BP_K);
        float4 la = lp4[0], lb = lp4[1];
        float lp[BP_K] = {la.x, la.y, la.z, la.w, lb.x, lb.y, lb.z, lb.w};
        float b[BP_K];
        float sum = 0.0f;
#pragma unroll
        for (int k = 0; k < BP_K; ++k) {
            b[k] = fmaxf(__expf(s[k] + lp[k]), BP_EPS);
            sum += b[k];
        }
        float inv = 1.0f / fmaxf(sum, BP_EPS);
        float4* o4 = (float4*)(out + (size_t)i * BP_K);
        o4[0] = {b[0] * inv, b[1] * inv, b[2] * inv, b[3] * inv};
        o4[1] = {b[4] * inv, b[5] * inv, b[6] * inv, b[7] * inv};
    }
}

extern "C" void kernel_launch(void* const* d_in, const int* in_sizes, int n_in,
                              void* d_out, int out_size, void* d_ws, size_t ws_size,
                              hipStream_t stream) {
    const float* prior     = (const float*)d_in[0];
    const float* msgs      = (const float*)d_in[1];
    const float* potential = (const float*)d_in[2];
    const int*   src       = (const int*)d_in[3];
    const int*   dst       = (const int*)d_in[4];
    const int ITERS = 5;   // fixed by setup_inputs

    int n  = in_sizes[0] / BP_K;
    int E  = in_sizes[3];
    int Eu = E / 2;
    int nbuck = (n + BNODES - 1) >> BSH;
    int nb32  = (E + 31) / 32;

    char* w = (char*)d_ws;
    _Float16* Wex = (_Float16*)w;  w += (size_t)E * 16;   // message array
    char*  R2     = w;             w += (size_t)E * 16;   // items/pos/eid then Wst
    float* LP     = (float*)w;     w += (size_t)n * BP_K * sizeof(float);
    int*   G      = (int*)w;       w += (size_t)NB1 * nbuck * sizeof(int);
    int*   Gpre   = (int*)w;       w += (size_t)NB1 * nbuck * sizeof(int);
    int*   total  = (int*)w;       w += (size_t)nbuck * sizeof(int);
    int*   base   = (int*)w;       w += (size_t)(nbuck + 1) * sizeof(int);
    int*   row    = (int*)w;       w += (size_t)(n + 1) * sizeof(int);
    int*   rev    = (int*)w;       w += (size_t)E * sizeof(int);
    int*   nod    = (int*)w;       w += (size_t)E * sizeof(int);
    int*   XS     = (int*)w;       w += (size_t)E * sizeof(int);
    int*   Sslot  = (int*)w;       w += (size_t)E * sizeof(int);
    int*   Alist  = (int*)w;       w += (size_t)n * sizeof(int);
    int*   nflag  = (int*)w;       w += (size_t)n * sizeof(int);
    unsigned int* bmap = (unsigned int*)w; w += (size_t)nb32 * sizeof(unsigned int);
    int*   cnts   = (int*)w;       w += 16 * sizeof(int);
    // R2 sub-aliases: items/pos/eid live only through iter1; Wst (staging,
    // slot-indexed) is first written at iter2 -> no overlap in time.
    int2*  items = (int2*)R2;
    int*   pos   = (int*)(R2 + (size_t)E * 8);
    int*   eid   = (int*)(R2 + (size_t)E * 12);
    _Float16* Wst = (_Float16*)R2;

    float* out = (float*)d_out;

    dim3 blk(256);
    dim3 grdEu((Eu + 255) / 256);
    dim3 grdNode((n + 7) / 8);     // 8 half-waves/block, half-wave per node
    size_t lds_hist = (size_t)nbuck * sizeof(int);

    // --- build: bucket-strip CSR + rev/nod/eid; zero per-launch state ---
    k_hist   <<<NB1, blk, lds_hist, stream>>>(src, dst, G, Eu, nbuck);
    k_scanG  <<<nbuck, NB1, 0, stream>>>(G, Gpre, total, nbuck);
    k_scanT  <<<1, 1024, 0, stream>>>(total, base, nbuck, row + n, E);
    k_scatter<<<NB1, blk, lds_hist, stream>>>(src, dst, Gpre, base, items, Eu, nbuck);
    k_csr    <<<nbuck, blk, 0, stream>>>(items, base, row, pos, eid, nod, n, Eu);
    k_rev    <<<grdEu, blk, 0, stream>>>(pos, rev, Eu);
    k_lp     <<<(n * BP_K + 255) / 256, blk, 0, stream>>>(prior, LP, n * BP_K);
    k_zero   <<<512, blk, 0, stream>>>(nflag, bmap, cnts, n, nb32);
    k_fill   <<<1024, blk, 0, stream>>>(Wex, potential, E);

    // --- iter1: the only full pass (fp32 gather); writes exceptions only ---
    k_step1<<<grdNode, blk, 0, stream>>>(msgs, eid, row, rev, LP, potential,
                                         Wex, XS, bmap, cnts, n);

    // --- iters 2..5: sparse (mark -> recompute staged -> apply) ---
    for (int t = 0; t < ITERS - 1; ++t) {
        int aidx = 1 + t;       // per-iteration counter slots (zeroed once)
        int sidx = 5 + t;
        k_mark  <<<512, blk, 0, stream>>>(row, LP, potential, XS, nod, rev,
                                          nflag, Alist, cnts, aidx, n);
        k_sparse<<<256, blk, 0, stream>>>(Wex, row, rev, LP, potential, Alist,
                                          nflag, Wst, Sslot, cnts, aidx, sidx);
        k_apply <<<256, blk, 0, stream>>>(Wex, Wst, Sslot, XS, bmap, cnts, sidx);
    }

    // --- final beliefs: full sequential read of Wex ---
    k_belief<<<grdNode, blk, 0, stream>>>(Wex, row, LP, out, n);
}

// Round 14
// 464.778 us; speedup vs baseline: 2.0919x; 1.1216x over previous
//
#include <hip/hip_runtime.h>
#include <hip/hip_fp16.h>

#define BP_EPS 1e-12f
#define BP_K 8
#define LOG_C 2.0f          // centering offset: stored = log(m) + LOG_C
#define CLAMP_SAFE -27.70f  // exact-test threshold (ln 1e-12 = -27.631, margin .07)
#define THR_HOT    -27.80f  // conservative node-level pre-test (extra fp-sum margin)
#define BSH 6               // nodes per bucket = 64
#define BNODES 64
#define NB1 512             // edge chunks for hist + scatter

typedef __attribute__((ext_vector_type(8))) _Float16 half8;

// ===========================================================================
// Sparse-exception BP (R13-verified) with the RMW-scatter passes removed:
//  - NO dense rev array (k_rev deleted): rev_of(j) = pos[pay[j]^1], gathered
//    on demand only where needed (exceptions / marked rows) -- reads, no RMW.
//  - NO k_fill: slots with bmap bit clear logically hold wbar; k_sparse gates
//    its row reads on the bitmap.
//  - belief computed sparsely: LP + deg*lw + corrections from XS slots.
// ===========================================================================

// ---- bucket-strip build (dense scatter runs; proven) ----------------------
__global__ void k_hist(const int* __restrict__ src, const int* __restrict__ dst,
                       int* __restrict__ G, int Eu, int nbuck) {
    extern __shared__ int h[];
    for (int i = threadIdx.x; i < nbuck; i += blockDim.x) h[i] = 0;
    __syncthreads();
    int per = (Eu + NB1 - 1) / NB1;
    int s0 = blockIdx.x * per;
    int s1 = min(s0 + per, Eu);
    for (int e = s0 + threadIdx.x; e < s1; e += blockDim.x) {
        atomicAdd(&h[src[e] >> BSH], 1);
        atomicAdd(&h[dst[e] >> BSH], 1);
    }
    __syncthreads();
    for (int b = threadIdx.x; b < nbuck; b += blockDim.x)
        G[blockIdx.x * nbuck + b] = h[b];
}

__global__ void k_scanG(const int* __restrict__ G, int* __restrict__ Gpre,
                        int* __restrict__ total, int nbuck) {
    __shared__ int buf[NB1];
    int b = blockIdx.x;
    int t = threadIdx.x;
    int v = G[t * nbuck + b];
    buf[t] = v;
    __syncthreads();
    for (int off = 1; off < NB1; off <<= 1) {
        int x = (t >= off) ? buf[t - off] : 0;
        __syncthreads();
        buf[t] += x;
        __syncthreads();
    }
    Gpre[b * NB1 + t] = buf[t] - v;
    if (t == NB1 - 1) total[b] = buf[t];
}

__global__ void k_scanT(const int* __restrict__ total, int* __restrict__ base,
                        int nbuck, int* __restrict__ row_n, int E) {
    __shared__ int buf[1024];
    int t = threadIdx.x;
    int carry = 0;
    for (int s = 0; s < nbuck; s += 1024) {
        int i = s + t;
        int v = (i < nbuck) ? total[i] : 0;
        buf[t] = v;
        __syncthreads();
        for (int off = 1; off < 1024; off <<= 1) {
            int x = (t >= off) ? buf[t - off] : 0;
            __syncthreads();
            buf[t] += x;
            __syncthreads();
        }
        if (i < nbuck) base[i] = carry + buf[t] - v;
        carry += buf[1023];
        __syncthreads();
    }
    if (t == 0) { base[nbuck] = carry; *row_n = E; }
}

__global__ void k_scatter(const int* __restrict__ src, const int* __restrict__ dst,
                          const int* __restrict__ Gpre, const int* __restrict__ base,
                          int2* __restrict__ items, int Eu, int nbuck) {
    extern __shared__ int cur[];
    int blk = blockIdx.x;
    for (int i = threadIdx.x; i < nbuck; i += blockDim.x)
        cur[i] = base[i] + Gpre[i * NB1 + blk];
    __syncthreads();
    int per = (Eu + NB1 - 1) / NB1;
    int s0 = blk * per;
    int s1 = min(s0 + per, Eu);
    for (int e = s0 + threadIdx.x; e < s1; e += blockDim.x) {
        int u = src[e], v = dst[e];
        int pu = atomicAdd(&cur[u >> BSH], 1);
        items[pu] = make_int2(u, (e << 1) | 1);
        int pv = atomicAdd(&cur[v >> BSH], 1);
        items[pv] = make_int2(v, (e << 1) | 0);
    }
}

// bucket -> per-node CSR; pos[payload]=slot (random, unavoidable),
// pay[slot]=payload and nod[slot]=node (dense strip writes).
__global__ void k_csr(const int2* __restrict__ items, const int* __restrict__ base,
                      int* __restrict__ row, int* __restrict__ pos,
                      int* __restrict__ pay, int* __restrict__ nod, int n) {
    __shared__ int deg[BNODES];
    __shared__ int cur[BNODES];
    int b = blockIdx.x;
    int lo = base[b], hi = base[b + 1];
    int node0 = b << BSH;
    if (threadIdx.x < BNODES) deg[threadIdx.x] = 0;
    __syncthreads();
    for (int i = lo + threadIdx.x; i < hi; i += blockDim.x)
        atomicAdd(&deg[items[i].x - node0], 1);
    __syncthreads();
    if (threadIdx.x == 0) {
        int acc = 0;
        for (int t = 0; t < BNODES; ++t) { int d = deg[t]; deg[t] = acc; acc += d; }
    }
    __syncthreads();
    if (threadIdx.x < BNODES) {
        int node = node0 + threadIdx.x;
        if (node < n) row[node] = lo + deg[threadIdx.x];
        cur[threadIdx.x] = deg[threadIdx.x];
    }
    __syncthreads();
    for (int i = lo + threadIdx.x; i < hi; i += blockDim.x) {
        int2 x = items[i];
        int p = atomicAdd(&cur[x.x - node0], 1);
        int slot = lo + p;
        pos[x.y] = slot;
        pay[slot] = x.y;
        nod[slot] = x.x;
    }
}

__global__ void k_lp(const float* __restrict__ prior, float* __restrict__ LP, int n8) {
    int i = blockIdx.x * blockDim.x + threadIdx.x;
    if (i < n8) LP[i] = __logf(fmaxf(prior[i], BP_EPS));
}

// zero per-launch state: node flags, slot bitmap, counters.
__global__ void k_zero(int* __restrict__ nflag, unsigned int* __restrict__ bmap,
                       int* __restrict__ cnts, int n, int nb) {
    int i = blockIdx.x * blockDim.x + threadIdx.x;
    int st = gridDim.x * blockDim.x;
    for (int j = i; j < n; j += st) nflag[j] = 0;
    for (int j = i; j < nb; j += st) bmap[j] = 0;
    if (i < 16) cnts[i] = 0;
}

// ---- emit math (hardware-verified path) -----------------------------------
__device__ inline half8 bp_emit_bb(const float* bb, const float* psi) {
    float mn[BP_K];
    float sum = 0.0f;
#pragma unroll
    for (int jj = 0; jj < BP_K; ++jj) {
        float acc = 0.0f;
#pragma unroll
        for (int k = 0; k < BP_K; ++k) acc += bb[k] * psi[k * BP_K + jj];
        mn[jj] = acc;
        sum += acc;
    }
    float inv = 1.0f / fmaxf(sum, BP_EPS);
    half8 o;
#pragma unroll
    for (int jj = 0; jj < BP_K; ++jj)
        o[jj] = (_Float16)(__logf(fmaxf(mn[jj] * inv, BP_EPS)) + LOG_C);
    return o;
}

__device__ inline half8 bp_emit(const float* s, const float* lm, const float* psi) {
    float bb[BP_K];
#pragma unroll
    for (int k = 0; k < BP_K; ++k)
        bb[k] = fmaxf(__expf(s[k] - lm[k]), BP_EPS);
    return bp_emit_bb(bb, psi);
}

__device__ inline bool bp_allclamp(const float* s, const float* lm) {
    float m = s[0] - lm[0];
#pragma unroll
    for (int k = 1; k < BP_K; ++k) m = fmaxf(m, s[k] - lm[k]);
    return m < CLAMP_SAFE;
}

__device__ inline bool neq16(const half8& a, const half8& b) {
    uint4 x, y;
    __builtin_memcpy(&x, &a, 16);
    __builtin_memcpy(&y, &b, 16);
    return ((x.x ^ y.x) | (x.y ^ y.y) | (x.z ^ y.z) | (x.w ^ y.w)) != 0u;
}

#define INIT_PSI()                                                             \
    __shared__ float psi[BP_K * BP_K];                                         \
    if (threadIdx.x < BP_K * BP_K) psi[threadIdx.x] = expf(potential[threadIdx.x]); \
    __syncthreads();

#define INIT_WBAR()                                                            \
    __shared__ __align__(16) unsigned short wsh[8];                            \
    if (threadIdx.x == 0) {                                                    \
        float bbc[BP_K];                                                       \
        for (int k = 0; k < BP_K; ++k) bbc[k] = BP_EPS;                        \
        half8 wb = bp_emit_bb(bbc, psi);                                       \
        for (int k = 0; k < BP_K; ++k) wsh[k] = ((unsigned short*)&wb)[k];     \
    }                                                                          \
    __syncthreads();                                                           \
    half8 wbar = *(half8*)wsh;

// ===========================================================================
// iter1 (only full pass): half-wave per node, gather fp32 msgs via pay->eid,
// butterfly S (+log prior); write ONLY non-clamped emits into Wex[pos[pay^1]]
// and record them in XS (bitmap-dedup'd).
// ===========================================================================
__global__ void __launch_bounds__(256) k_step1(
        const float* __restrict__ msgs, const int* __restrict__ pay,
        const int* __restrict__ pos, const int* __restrict__ row,
        const float* __restrict__ LP, const float* __restrict__ potential,
        _Float16* __restrict__ Wex, int* __restrict__ XS,
        unsigned int* __restrict__ bmap, int* __restrict__ cnts, int n, int Eu) {
    INIT_PSI();

    int half = threadIdx.x >> 5;
    int sl = threadIdx.x & 31;
    int i = blockIdx.x * 8 + half;
    if (i >= n) return;

    int r0 = row[i];
    int r1 = row[i + 1];
    int j0 = r0 + sl;
    int j1 = j0 + 32;
    bool h0 = j0 < r1;
    bool h1 = j1 < r1;

    float s[BP_K];
#pragma unroll
    for (int k = 0; k < BP_K; ++k) s[k] = 0.0f;

    float lm0[BP_K], lm1[BP_K];
    int py0 = 0, py1 = 0;

#define LOADF(J, LM, PY)                                                      \
    {                                                                         \
        PY = pay[J];                                                          \
        int id = (PY >> 1) + (PY & 1) * Eu;                                   \
        const float4* m4 = (const float4*)(msgs + (size_t)id * BP_K);         \
        float4 x = m4[0], y = m4[1];                                          \
        float v[BP_K] = {x.x, x.y, x.z, x.w, y.x, y.y, y.z, y.w};             \
        _Pragma("unroll")                                                     \
        for (int k = 0; k < BP_K; ++k) LM[k] = __logf(fmaxf(v[k], BP_EPS));   \
    }

    if (h0) {
        LOADF(j0, lm0, py0);
#pragma unroll
        for (int k = 0; k < BP_K; ++k) s[k] += lm0[k];
    }
    if (h1) {
        LOADF(j1, lm1, py1);
#pragma unroll
        for (int k = 0; k < BP_K; ++k) s[k] += lm1[k];
    }
    for (int j = j0 + 64; j < r1; j += 32) {
        float t[BP_K];
        int pyt;
        LOADF(j, t, pyt);
#pragma unroll
        for (int k = 0; k < BP_K; ++k) s[k] += t[k];
    }

#pragma unroll
    for (int off = 16; off >= 1; off >>= 1) {
#pragma unroll
        for (int k = 0; k < BP_K; ++k) s[k] += __shfl_xor(s[k], off);
    }
    {
        const float4* lp4 = (const float4*)(LP + (size_t)i * BP_K);
        float4 la = lp4[0], lb = lp4[1];
        s[0] += la.x; s[1] += la.y; s[2] += la.z; s[3] += la.w;
        s[4] += lb.x; s[5] += lb.y; s[6] += lb.z; s[7] += lb.w;
    }

#define EMIT1(LM, PY)                                                         \
    if (!bp_allclamp(s, LM)) {                                                \
        int rv = pos[(PY) ^ 1];                                               \
        *(half8*)(Wex + (size_t)rv * BP_K) = bp_emit(s, LM, psi);             \
        unsigned int mbit = 1u << (rv & 31);                                  \
        if (!(atomicOr(&bmap[rv >> 5], mbit) & mbit)) {                       \
            int idx = atomicAdd(&cnts[0], 1);                                 \
            XS[idx] = rv;                                                     \
        }                                                                     \
    }

    if (h0) EMIT1(lm0, py0)
    if (h1) EMIT1(lm1, py1)
    for (int j = j0 + 64; j < r1; j += 32) {
        float t[BP_K];
        int pyt;
        LOADF(j, t, pyt);
        EMIT1(t, pyt)
    }
#undef EMIT1
#undef LOADF
}

// ===========================================================================
// sparse iteration t: mark (hot nodes + XS neighborhoods) -> recompute marked
// nodes (bitmap-gated reads, changes staged compactly) -> apply.
// ===========================================================================
__global__ void __launch_bounds__(256) k_mark(
        const int* __restrict__ row, const float* __restrict__ LP,
        const float* __restrict__ potential, const int* __restrict__ XS,
        const int* __restrict__ nod, const int* __restrict__ pay,
        const int* __restrict__ pos, int* __restrict__ nflag,
        int* __restrict__ Alist, int* __restrict__ cnts, int aidx, int n) {
    INIT_PSI();
    INIT_WBAR();
    float lw[BP_K];
#pragma unroll
    for (int k = 0; k < BP_K; ++k) lw[k] = (float)wbar[k] - LOG_C;

    int tid = blockIdx.x * blockDim.x + threadIdx.x;
    int st = gridDim.x * blockDim.x;

#define MARK(NODE)                                                            \
    {                                                                         \
        int nd_ = (NODE);                                                     \
        if (atomicExch(&nflag[nd_], 1) == 0) {                                \
            int ix = atomicAdd(&cnts[aidx], 1);                               \
            Alist[ix] = nd_;                                                  \
        }                                                                     \
    }

    // hot nodes: all-wbar-input emit test could fail the clamp
    for (int i = tid; i < n; i += st) {
        float dg = (float)(row[i + 1] - row[i]);
        const float4* lp4 = (const float4*)(LP + (size_t)i * BP_K);
        float4 la = lp4[0], lb = lp4[1];
        float lp[BP_K] = {la.x, la.y, la.z, la.w, lb.x, lb.y, lb.z, lb.w};
        float m = -1e30f;
#pragma unroll
        for (int k = 0; k < BP_K; ++k)
            m = fmaxf(m, dg * lw[k] + lp[k] - lw[k]);
        if (m >= THR_HOT) MARK(i)
    }
    // XS neighborhoods: consumer (S changed) and producer (must re-emit)
    int xc = cnts[0];
    for (int e = tid; e < xc; e += st) {
        int s = XS[e];
        MARK(nod[s])
        MARK(nod[pos[pay[s] ^ 1]])
    }
#undef MARK
}

__global__ void __launch_bounds__(256) k_sparse(
        const _Float16* __restrict__ Wex, const int* __restrict__ row,
        const int* __restrict__ pay, const int* __restrict__ pos,
        const unsigned int* __restrict__ bmap, const float* __restrict__ LP,
        const float* __restrict__ potential, const int* __restrict__ Alist,
        int* __restrict__ nflag, int* __restrict__ Sslot,
        _Float16* __restrict__ Sval, int* __restrict__ cnts, int aidx, int sidx) {
    INIT_PSI();
    INIT_WBAR();

    int half = threadIdx.x >> 5;
    int sl = threadIdx.x & 31;
    int cntA = cnts[aidx];

#define GATED(J, H)                                                           \
    half8 H;                                                                  \
    {                                                                         \
        bool ex_ = (bmap[(J) >> 5] >> ((J) & 31)) & 1;                        \
        H = ex_ ? *(const half8*)(Wex + (size_t)(J) * BP_K) : wbar;           \
    }

    for (int a = blockIdx.x * 8 + half; a < cntA; a += gridDim.x * 8) {
        int i = Alist[a];
        int r0 = row[i];
        int r1 = row[i + 1];

        float s[BP_K];
#pragma unroll
        for (int k = 0; k < BP_K; ++k) s[k] = 0.0f;

        for (int j = r0 + sl; j < r1; j += 32) {
            GATED(j, h)
#pragma unroll
            for (int k = 0; k < BP_K; ++k) s[k] += (float)h[k] - LOG_C;
        }
#pragma unroll
        for (int off = 16; off >= 1; off >>= 1) {
#pragma unroll
            for (int k = 0; k < BP_K; ++k) s[k] += __shfl_xor(s[k], off);
        }
        {
            const float4* lp4 = (const float4*)(LP + (size_t)i * BP_K);
            float4 la = lp4[0], lb = lp4[1];
            s[0] += la.x; s[1] += la.y; s[2] += la.z; s[3] += la.w;
            s[4] += lb.x; s[5] += lb.y; s[6] += lb.z; s[7] += lb.w;
        }

        for (int j = r0 + sl; j < r1; j += 32) {
            GATED(j, h)
            float lm[BP_K];
#pragma unroll
            for (int k = 0; k < BP_K; ++k) lm[k] = (float)h[k] - LOG_C;
            half8 nv = bp_allclamp(s, lm) ? wbar : bp_emit(s, lm, psi);
            int rv = pos[pay[j] ^ 1];
            GATED(rv, cv)
            if (neq16(cv, nv)) {
                int idx = atomicAdd(&cnts[sidx], 1);
                Sslot[idx] = rv;
                *(half8*)(Sval + (size_t)idx * BP_K) = nv;   // staged compactly
            }
        }
        if (sl == 0) nflag[i] = 0;   // reset for next iteration's mark
    }
#undef GATED
}

__global__ void __launch_bounds__(256) k_apply(
        _Float16* __restrict__ Wex, const int* __restrict__ Sslot,
        const _Float16* __restrict__ Sval, int* __restrict__ XS,
        unsigned int* __restrict__ bmap, int* __restrict__ cnts, int sidx) {
    int cnt = cnts[sidx];
    int st = gridDim.x * blockDim.x;
    for (int e = blockIdx.x * blockDim.x + threadIdx.x; e < cnt; e += st) {
        int rv = Sslot[e];
        *(half8*)(Wex + (size_t)rv * BP_K) = *(const half8*)(Sval + (size_t)e * BP_K);
        unsigned int mbit = 1u << (rv & 31);
        if (!(atomicOr(&bmap[rv >> 5], mbit) & mbit)) {
            int idx = atomicAdd(&cnts[0], 1);
            XS[idx] = rv;
        }
    }
}

// ===========================================================================
// sparse beliefs: BA = LP + deg*lw; += (lm - lw) per XS slot; normalize.
// ===========================================================================
__global__ void __launch_bounds__(256) kb_base(
        const int* __restrict__ row, const float* __restrict__ LP,
        const float* __restrict__ potential, float* __restrict__ BA, int n) {
    INIT_PSI();
    INIT_WBAR();
    float lw[BP_K];
#pragma unroll
    for (int k = 0; k < BP_K; ++k) lw[k] = (float)wbar[k] - LOG_C;
    int st = gridDim.x * blockDim.x;
    for (int i = blockIdx.x * blockDim.x + threadIdx.x; i < n; i += st) {
        float dg = (float)(row[i + 1] - row[i]);
        const float4* lp4 = (const float4*)(LP + (size_t)i * BP_K);
        float4 la = lp4[0], lb = lp4[1];
        float lp[BP_K] = {la.x, la.y, la.z, la.w, lb.x, lb.y, lb.z, lb.w};
        float4* o4 = (float4*)(BA + (size_t)i * BP_K);
        o4[0] = {lp[0] + dg * lw[0], lp[1] + dg * lw[1],
                 lp[2] + dg * lw[2], lp[3] + dg * lw[3]};
        o4[1] = {lp[4] + dg * lw[4], lp[5] + dg * lw[5],
                 lp[6] + dg * lw[6], lp[7] + dg * lw[7]};
    }
}

__global__ void __launch_bounds__(256) kb_corr(
        const _Float16* __restrict__ Wex, const int* __restrict__ XS,
        const int* __restrict__ nod, const float* __restrict__ potential,
        float* __restrict__ BA, const int* __restrict__ cnts) {
    INIT_PSI();
    INIT_WBAR();
    float lw[BP_K];
#pragma unroll
    for (int k = 0; k < BP_K; ++k) lw[k] = (float)wbar[k] - LOG_C;
    int cnt = cnts[0];
    int st = gridDim.x * blockDim.x;
    for (int e = blockIdx.x * blockDim.x + threadIdx.x; e < cnt; e += st) {
        int s = XS[e];
        int i = nod[s];
        half8 h = *(const half8*)(Wex + (size_t)s * BP_K);
#pragma unroll
        for (int k = 0; k < BP_K; ++k)
            atomicAdd(&BA[(size_t)i * BP_K + k], ((float)h[k] - LOG_C) - lw[k]);
    }
}

__global__ void __launch_bounds__(256) kb_norm(
        const float* __restrict__ BA, float* __restrict__ out, int n) {
    int st = gridDim.x * blockDim.x;
    for (int i = blockIdx.x * blockDim.x + threadIdx.x; i < n; i += st) {
        const float4* s4 = (const float4*)(BA + (size_t)i * BP_K);
        float4 sa = s4[0], sb = s4[1];
        float s[BP_K] = {sa.x, sa.y, sa.z, sa.w, sb.x, sb.y, sb.z, sb.w};
        float b[BP_K];
        float sum = 0.0f;
#pragma unroll
        for (int k = 0; k < BP_K; ++k) {
            b[k] = fmaxf(__expf(s[k]), BP_EPS);
            sum += b[k];
        }
        float inv = 1.0f / fmaxf(sum, BP_EPS);
        float4* o4 = (float4*)(out + (size_t)i * BP_K);
        o4[0] = {b[0] * inv, b[1] * inv, b[2] * inv, b[3] * inv};
        o4[1] = {b[4] * inv, b[5] * inv, b[6] * inv, b[7] * inv};
    }
}

extern "C" void kernel_launch(void* const* d_in, const int* in_sizes, int n_in,
                              void* d_out, int out_size, void* d_ws, size_t ws_size,
                              hipStream_t stream) {
    const float* prior     = (const float*)d_in[0];
    const float* msgs      = (const float*)d_in[1];
    const float* potential = (const float*)d_in[2];
    const int*   src       = (const int*)d_in[3];
    const int*   dst       = (const int*)d_in[4];
    const int ITERS = 5;   // fixed by setup_inputs

    int n  = in_sizes[0] / BP_K;
    int E  = in_sizes[3];
    int Eu = E / 2;
    int nbuck = (n + BNODES - 1) >> BSH;
    int nb32  = (E + 31) / 32;

    char* w = (char*)d_ws;
    _Float16* Wex = (_Float16*)w;  w += (size_t)E * 16;           // 51.2 MB
    int2*  items  = (int2*)w;      w += (size_t)E * sizeof(int2); // 51.2 MB (build only)
    int*   pos    = (int*)w;       w += (size_t)E * sizeof(int);
    int*   pay    = (int*)w;       w += (size_t)E * sizeof(int);
    int*   nod    = (int*)w;       w += (size_t)E * sizeof(int);
    int*   XS     = (int*)w;       w += (size_t)E * sizeof(int);
    int*   Sslot  = (int*)w;       w += (size_t)Eu * sizeof(int);
    _Float16* Sval = (_Float16*)w; w += (size_t)Eu * 16;          // compact staging
    float* LP     = (float*)w;     w += (size_t)n * BP_K * sizeof(float);
    float* BA     = (float*)w;     w += (size_t)n * BP_K * sizeof(float);
    int*   G      = (int*)w;       w += (size_t)NB1 * nbuck * sizeof(int);
    int*   Gpre   = (int*)w;       w += (size_t)NB1 * nbuck * sizeof(int);
    int*   total  = (int*)w;       w += (size_t)nbuck * sizeof(int);
    int*   base   = (int*)w;       w += (size_t)(nbuck + 1) * sizeof(int);
    int*   row    = (int*)w;       w += (size_t)(n + 1) * sizeof(int);
    int*   Alist  = (int*)w;       w += (size_t)n * sizeof(int);
    int*   nflag  = (int*)w;       w += (size_t)n * sizeof(int);
    unsigned int* bmap = (unsigned int*)w; w += (size_t)nb32 * sizeof(unsigned int);
    int*   cnts   = (int*)w;       w += 16 * sizeof(int);

    float* out = (float*)d_out;

    dim3 blk(256);
    dim3 grdEu((Eu + 255) / 256);
    dim3 grdNode((n + 7) / 8);     // 8 half-waves/block, half-wave per node
    size_t lds_hist = (size_t)nbuck * sizeof(int);

    // --- build: bucket-strip CSR (row/pos/pay/nod); zero per-launch state ---
    k_hist   <<<NB1, blk, lds_hist, stream>>>(src, dst, G, Eu, nbuck);
    k_scanG  <<<nbuck, NB1, 0, stream>>>(G, Gpre, total, nbuck);
    k_scanT  <<<1, 1024, 0, stream>>>(total, base, nbuck, row + n, E);
    k_scatter<<<NB1, blk, lds_hist, stream>>>(src, dst, Gpre, base, items, Eu, nbuck);
    k_csr    <<<nbuck, blk, 0, stream>>>(items, base, row, pos, pay, nod, n);
    k_lp     <<<(n * BP_K + 255) / 256, blk, 0, stream>>>(prior, LP, n * BP_K);
    k_zero   <<<512, blk, 0, stream>>>(nflag, bmap, cnts, n, nb32);

    // --- iter1: the only full pass (fp32 gather); writes exceptions only ---
    k_step1<<<grdNode, blk, 0, stream>>>(msgs, pay, pos, row, LP, potential,
                                         Wex, XS, bmap, cnts, n, Eu);

    // --- iters 2..5: sparse (mark -> recompute staged -> apply) ---
    for (int t = 0; t < ITERS - 1; ++t) {
        int aidx = 1 + t;       // per-iteration counter slots (zeroed once)
        int sidx = 5 + t;
        k_mark  <<<512, blk, 0, stream>>>(row, LP, potential, XS, nod, pay, pos,
                                          nflag, Alist, cnts, aidx, n);
        k_sparse<<<256, blk, 0, stream>>>(Wex, row, pay, pos, bmap, LP, potential,
                                          Alist, nflag, Sslot, Sval, cnts,
                                          aidx, sidx);
        k_apply <<<256, blk, 0, stream>>>(Wex, Sslot, Sval, XS, bmap, cnts, sidx);
    }

    // --- sparse beliefs ---
    kb_base<<<512, blk, 0, stream>>>(row, LP, potential, BA, n);
    kb_corr<<<256, blk, 0, stream>>>(Wex, XS, nod, potential, BA, cnts);
    kb_norm<<<512, blk, 0, stream>>>(BA, out, n);
}